// Round 1
// baseline (382.500 us; speedup 1.0000x reference)
//
#include <hip/hip_runtime.h>
#include <hip/hip_bf16.h>

typedef __bf16 bf16x8 __attribute__((ext_vector_type(8)));
typedef float f32x4 __attribute__((ext_vector_type(4)));

#define E_DIM 1024
#define HD 64
#define NH 16

__device__ __forceinline__ float toF(float x) { return x; }
__device__ __forceinline__ float toF(__hip_bfloat16 x) { return __bfloat162float(x); }
__device__ __forceinline__ void storeOut(float* p, float v) { *p = v; }
__device__ __forceinline__ void storeOut(__hip_bfloat16* p, float v) { *p = __float2bfloat16(v); }

// ---------------- cast fp32 -> bf16 (vectorized) ----------------
__global__ void cast_f32_bf16_kernel(const float* __restrict__ in, __hip_bfloat16* __restrict__ o, int n) {
    int i = (blockIdx.x * blockDim.x + threadIdx.x) * 4;
    if (i + 3 < n) {
        float4 v = *reinterpret_cast<const float4*>(in + i);
        __hip_bfloat16 t[4] = {__float2bfloat16(v.x), __float2bfloat16(v.y),
                               __float2bfloat16(v.z), __float2bfloat16(v.w)};
        *reinterpret_cast<uint2*>(o + i) = *reinterpret_cast<uint2*>(t);
    }
}

// ---------------- tiled cast-transpose: out[c][r] = in[r][c] ----------------
template<typename InT>
__global__ void transpose_cast_kernel(const InT* __restrict__ in, int ldi,
                                      __hip_bfloat16* __restrict__ out, int ldo,
                                      int R, int C) {
    __shared__ float tile[32][33];
    const int bx = blockIdx.x * 32;  // r
    const int by = blockIdx.y * 32;  // c
    const int tx = threadIdx.x & 31, ty = threadIdx.x >> 5;  // 32 x 8
#pragma unroll
    for (int j = 0; j < 4; ++j) {
        int r = bx + ty + j * 8, c = by + tx;
        tile[ty + j * 8][tx] = toF(in[(size_t)r * ldi + c]);
    }
    __syncthreads();
#pragma unroll
    for (int j = 0; j < 4; ++j) {
        int c = by + ty + j * 8, r = bx + tx;
        out[(size_t)c * ldo + r] = __float2bfloat16(tile[tx][ty + j * 8]);
    }
}

// ---------------- concat bk|bv ----------------
__global__ void concat_bias_kernel(const float* __restrict__ bk, const float* __restrict__ bv,
                                   float* __restrict__ bkv) {
    int i = threadIdx.x;  // 128 threads
    bkv[i] = (i < HD) ? bk[i] : bv[i - HD];
}

// ---------------- mask -> 64-bit words via ballot ----------------
__global__ void maskbits_kernel(const int* __restrict__ mask, unsigned long long* __restrict__ mb,
                                int nwords) {
    int gtid = blockIdx.x * blockDim.x + threadIdx.x;
    int wid = gtid >> 6, lane = gtid & 63;
    int nw = (gridDim.x * blockDim.x) >> 6;
    for (int w = wid; w < nwords; w += nw) {
        int v = mask[(size_t)w * 64 + lane];
        unsigned long long b = __ballot(v != 0);
        if (lane == 0) mb[w] = b;
    }
}

// ---------------- bf16 GEMM: C[M][N] = A[M][K] * Bt[N][K]^T, epilogue (acc+bias)*scale ----------------
template<typename OutT>
__global__ __launch_bounds__(256)
void gemm_bt_kernel(const __hip_bfloat16* __restrict__ A,
                    const __hip_bfloat16* __restrict__ Bt,
                    const float* __restrict__ bias,
                    OutT* __restrict__ C,
                    int M, int N, int K, float scale) {
    constexpr int BM = 128, BN = 128, BK = 32;
    __shared__ __align__(16) unsigned char lA[BM * BK * 2];  // [row][64B] swizzled
    __shared__ __align__(16) unsigned char lB[BN * BK * 2];
    const int ntn = N / BN;
    const int tm = blockIdx.x / ntn, tn = blockIdx.x % ntn;
    const int tid = threadIdx.x, lane = tid & 63, wave = tid >> 6;
    const int l15 = lane & 15, l4 = lane >> 4;
    const int wm = (wave >> 1) * 64, wn = (wave & 1) * 64;
    const int r0 = tm * BM, c0 = tn * BN;
    f32x4 z4 = {0.f, 0.f, 0.f, 0.f};
    f32x4 acc[4][4];
#pragma unroll
    for (int mi = 0; mi < 4; ++mi)
#pragma unroll
        for (int ni = 0; ni < 4; ++ni) acc[mi][ni] = z4;

    for (int k0 = 0; k0 < K; k0 += BK) {
#pragma unroll
        for (int i = 0; i < 2; ++i) {
            int id = tid + i * 256;        // 0..511 : 16B chunks
            int row = id >> 2;             // 0..127
            int cb = (id & 3) * 16;        // byte in 64B row
            int sw = cb ^ ((row & 3) << 4);
            uint4 va = *reinterpret_cast<const uint4*>(
                reinterpret_cast<const unsigned char*>(A + (size_t)(r0 + row) * K + k0) + cb);
            *reinterpret_cast<uint4*>(&lA[row * 64 + sw]) = va;
            uint4 vb = *reinterpret_cast<const uint4*>(
                reinterpret_cast<const unsigned char*>(Bt + (size_t)(c0 + row) * K + k0) + cb);
            *reinterpret_cast<uint4*>(&lB[row * 64 + sw]) = vb;
        }
        __syncthreads();
        bf16x8 af[4], bf[4];
#pragma unroll
        for (int mi = 0; mi < 4; ++mi) {
            int row = wm + mi * 16 + l15;
            af[mi] = *reinterpret_cast<const bf16x8*>(&lA[row * 64 + ((l4 * 16) ^ ((row & 3) << 4))]);
        }
#pragma unroll
        for (int ni = 0; ni < 4; ++ni) {
            int row = wn + ni * 16 + l15;
            bf[ni] = *reinterpret_cast<const bf16x8*>(&lB[row * 64 + ((l4 * 16) ^ ((row & 3) << 4))]);
        }
#pragma unroll
        for (int mi = 0; mi < 4; ++mi)
#pragma unroll
            for (int ni = 0; ni < 4; ++ni)
                acc[mi][ni] = __builtin_amdgcn_mfma_f32_16x16x32_bf16(af[mi], bf[ni], acc[mi][ni], 0, 0, 0);
        __syncthreads();
    }
#pragma unroll
    for (int ni = 0; ni < 4; ++ni) {
        int col = c0 + wn + ni * 16 + l15;
        float b = bias[col];
#pragma unroll
        for (int mi = 0; mi < 4; ++mi) {
            int row = r0 + wm + mi * 16 + l4 * 4;
#pragma unroll
            for (int r = 0; r < 4; ++r) {
                float v = (acc[mi][ni][r] + b) * scale;
                storeOut(C + (size_t)(row + r) * N + col, v);
            }
        }
    }
}

// ---------------- MQA flash attention ----------------
// qb [S][1024] bf16 prescaled by 1/8; kvb [S][128] (cols 0..63 = K); vtb [64][S]; out attnb [S][1024]
__global__ __launch_bounds__(256)
void mqa_kernel(const __hip_bfloat16* __restrict__ qb,
                const __hip_bfloat16* __restrict__ kvb,
                const __hip_bfloat16* __restrict__ vtb,
                const unsigned long long* __restrict__ mbits,
                __hip_bfloat16* __restrict__ attnb,
                int S) {
    constexpr int KB = 64;
    __shared__ __align__(16) unsigned char lK[KB * 128];      // [kpos][128B] swizzled
    __shared__ __align__(16) unsigned char lV[HD * KB * 2];   // [d][128B]   swizzled
    __shared__ __align__(16) unsigned char lP[4][16 * 128];   // per-wave P, swizzled
    const int h = blockIdx.y;
    const int q0 = blockIdx.x * 64;
    const int tid = threadIdx.x, lane = tid & 63, w = tid >> 6;
    const int l15 = lane & 15, l4 = lane >> 4;
    const int nw64 = S / 64;

    // Q fragments in registers (reused across all K tiles)
    bf16x8 qf[2];
    {
        const __hip_bfloat16* qp = qb + (size_t)(q0 + w * 16 + l15) * E_DIM + h * HD + l4 * 8;
        qf[0] = *reinterpret_cast<const bf16x8*>(qp);
        qf[1] = *reinterpret_cast<const bf16x8*>(qp + 32);
    }
    float rm[4], rl[4];
    f32x4 z4 = {0.f, 0.f, 0.f, 0.f};
    f32x4 acc[4];
#pragma unroll
    for (int r = 0; r < 4; ++r) { rm[r] = -1e30f; rl[r] = 0.f; }
#pragma unroll
    for (int dt = 0; dt < 4; ++dt) acc[dt] = z4;

    for (int t = 0; t < S / KB; ++t) {
        const int k0 = t * KB;
        // stage K tile [64][64] and V^T tile [64][64]
#pragma unroll
        for (int i = 0; i < 2; ++i) {
            int id = tid + i * 256;       // 0..511
            int row = id >> 3;            // 0..63
            int cb = (id & 7) * 16;       // byte in 128B row
            int sw = cb ^ ((row & 7) << 4);
            uint4 vk = *reinterpret_cast<const uint4*>(
                reinterpret_cast<const unsigned char*>(kvb + (size_t)(k0 + row) * 128) + cb);
            *reinterpret_cast<uint4*>(&lK[row * 128 + sw]) = vk;
            uint4 vv = *reinterpret_cast<const uint4*>(
                reinterpret_cast<const unsigned char*>(vtb + (size_t)row * S + k0) + cb);
            *reinterpret_cast<uint4*>(&lV[row * 128 + sw]) = vv;
        }
        __syncthreads();

        // QK^T : s4[kt] covers kpos kt*16..+15 for this wave's 16 q rows
        f32x4 s4[4];
#pragma unroll
        for (int kt = 0; kt < 4; ++kt) {
            f32x4 z = z4;
#pragma unroll
            for (int dh = 0; dh < 2; ++dh) {
                int row = kt * 16 + l15;
                bf16x8 kf = *reinterpret_cast<const bf16x8*>(
                    &lK[row * 128 + ((l4 * 16 + dh * 64) ^ ((row & 7) << 4))]);
                z = __builtin_amdgcn_mfma_f32_16x16x32_bf16(qf[dh], kf, z, 0, 0, 0);
            }
            s4[kt] = z;
        }

        // mask (cheap when word == all-ones)
#pragma unroll
        for (int r = 0; r < 4; ++r) {
            int qrow = l4 * 4 + r;
            unsigned long long wb = mbits[(size_t)(q0 + w * 16 + qrow) * nw64 + t];
            if (wb != ~0ull) {
#pragma unroll
                for (int kt = 0; kt < 4; ++kt)
                    if (!((wb >> (l15 + kt * 16)) & 1)) s4[kt][r] = -10000.0f;
            }
        }

        // online softmax, write P (bf16) to per-wave swizzled LDS
#pragma unroll
        for (int r = 0; r < 4; ++r) {
            int qrow = l4 * 4 + r;
            float mt = fmaxf(fmaxf(s4[0][r], s4[1][r]), fmaxf(s4[2][r], s4[3][r]));
#pragma unroll
            for (int o = 1; o < 16; o <<= 1) mt = fmaxf(mt, __shfl_xor(mt, o, 64));
            float mn = fmaxf(rm[r], mt);
            float al = __expf(rm[r] - mn);
            float ps = 0.f;
#pragma unroll
            for (int kt = 0; kt < 4; ++kt) {
                float p = __expf(s4[kt][r] - mn);
                ps += p;
                int kb2 = ((l15 + kt * 16) * 2) ^ ((qrow & 7) << 4);
                *reinterpret_cast<__hip_bfloat16*>(&lP[w][qrow * 128 + kb2]) = __float2bfloat16(p);
            }
#pragma unroll
            for (int o = 1; o < 16; o <<= 1) ps += __shfl_xor(ps, o, 64);
            rl[r] = rl[r] * al + ps;
            rm[r] = mn;
#pragma unroll
            for (int dt = 0; dt < 4; ++dt) acc[dt][r] *= al;
        }

        // PV : acc[dt] += P * V
        bf16x8 pa[2];
#pragma unroll
        for (int kk = 0; kk < 2; ++kk) {
            int row = l15;
            pa[kk] = *reinterpret_cast<const bf16x8*>(
                &lP[w][row * 128 + ((l4 * 16 + kk * 64) ^ ((row & 7) << 4))]);
        }
#pragma unroll
        for (int dt = 0; dt < 4; ++dt)
#pragma unroll
            for (int kk = 0; kk < 2; ++kk) {
                int row = dt * 16 + l15;
                bf16x8 vf = *reinterpret_cast<const bf16x8*>(
                    &lV[row * 128 + ((l4 * 16 + kk * 64) ^ ((row & 7) << 4))]);
                acc[dt] = __builtin_amdgcn_mfma_f32_16x16x32_bf16(pa[kk], vf, acc[dt], 0, 0, 0);
            }
        __syncthreads();
    }

    // epilogue: attnb[row][h*64+d] = acc/l
#pragma unroll
    for (int dt = 0; dt < 4; ++dt)
#pragma unroll
        for (int r = 0; r < 4; ++r) {
            int row = q0 + w * 16 + l4 * 4 + r;
            int col = h * HD + dt * 16 + l15;
            attnb[(size_t)row * E_DIM + col] = __float2bfloat16(acc[dt][r] / rl[r]);
        }
}

// ---------------- host launch ----------------
extern "C" void kernel_launch(void* const* d_in, const int* in_sizes, int n_in,
                              void* d_out, int out_size, void* d_ws, size_t ws_size,
                              hipStream_t stream) {
    (void)n_in; (void)out_size; (void)ws_size;
    const float* x  = (const float*)d_in[0];
    const int* mask = (const int*)d_in[1];
    const float* Wq = (const float*)d_in[2];
    const float* bq = (const float*)d_in[3];
    const float* Wk = (const float*)d_in[4];
    const float* bk = (const float*)d_in[5];
    const float* Wv = (const float*)d_in[6];
    const float* bv = (const float*)d_in[7];
    const float* Wo = (const float*)d_in[8];
    const float* bo = (const float*)d_in[9];
    float* out = (float*)d_out;

    const int E = E_DIM;
    const int S = in_sizes[0] / E;

    char* ws = (char*)d_ws;
    size_t off = 0;
    auto alloc = [&](size_t b) { char* p = ws + off; off += (b + 255) & ~(size_t)255; return p; };
    __hip_bfloat16* xb    = (__hip_bfloat16*)alloc((size_t)S * E * 2);
    __hip_bfloat16* wqT   = (__hip_bfloat16*)alloc((size_t)E * E * 2);
    __hip_bfloat16* wkvT  = (__hip_bfloat16*)alloc((size_t)128 * E * 2);
    __hip_bfloat16* woT   = (__hip_bfloat16*)alloc((size_t)E * E * 2);
    __hip_bfloat16* qb    = (__hip_bfloat16*)alloc((size_t)S * E * 2);
    __hip_bfloat16* kvb   = (__hip_bfloat16*)alloc((size_t)S * 128 * 2);
    __hip_bfloat16* vtb   = (__hip_bfloat16*)alloc((size_t)HD * S * 2);
    __hip_bfloat16* attnb = (__hip_bfloat16*)alloc((size_t)S * E * 2);
    float* bkv = (float*)alloc(512);
    unsigned long long* mbits = (unsigned long long*)alloc((size_t)S * (S / 64) * 8);

    cast_f32_bf16_kernel<<<dim3((S * E / 4 + 255) / 256), dim3(256), 0, stream>>>(x, xb, S * E);
    transpose_cast_kernel<float><<<dim3(E / 32, E / 32), dim3(256), 0, stream>>>(Wq, E, wqT, E, E, E);
    transpose_cast_kernel<float><<<dim3(E / 32, HD / 32), dim3(256), 0, stream>>>(Wk, HD, wkvT, E, E, HD);
    transpose_cast_kernel<float><<<dim3(E / 32, HD / 32), dim3(256), 0, stream>>>(Wv, HD, wkvT + (size_t)HD * E, E, E, HD);
    transpose_cast_kernel<float><<<dim3(E / 32, E / 32), dim3(256), 0, stream>>>(Wo, E, woT, E, E, E);
    concat_bias_kernel<<<dim3(1), dim3(128), 0, stream>>>(bk, bv, bkv);
    maskbits_kernel<<<dim3(1024), dim3(256), 0, stream>>>(mask, mbits, S * (S / 64));

    // q = (x @ Wq + bq) * 1/sqrt(64)   -> bf16 [S][1024]
    gemm_bt_kernel<__hip_bfloat16><<<dim3((S / 128) * (E / 128)), dim3(256), 0, stream>>>(
        xb, wqT, bq, qb, S, E, E, 0.125f);
    // kv = x @ [Wk|Wv] + [bk|bv]       -> bf16 [S][128]
    gemm_bt_kernel<__hip_bfloat16><<<dim3(S / 128), dim3(256), 0, stream>>>(
        xb, wkvT, bkv, kvb, S, 128, E, 1.0f);
    // v^T [64][S]
    transpose_cast_kernel<__hip_bfloat16><<<dim3(S / 32, HD / 32), dim3(256), 0, stream>>>(
        kvb + HD, 128, vtb, S, S, HD);
    // attention
    mqa_kernel<<<dim3(S / 64, NH), dim3(256), 0, stream>>>(qb, kvb, vtb, mbits, attnb, S);
    // out = attn @ Wo + bo  (fp32)
    gemm_bt_kernel<float><<<dim3((S / 128) * (E / 128)), dim3(256), 0, stream>>>(
        attnb, woT, bo, out, S, E, E, 1.0f);
}

// Round 2
// 322.442 us; speedup vs baseline: 1.1863x; 1.1863x over previous
//
#include <hip/hip_runtime.h>
#include <hip/hip_bf16.h>

typedef __bf16 bf16x8 __attribute__((ext_vector_type(8)));
typedef float f32x4 __attribute__((ext_vector_type(4)));
typedef float f32x16 __attribute__((ext_vector_type(16)));
typedef unsigned int uint2v __attribute__((ext_vector_type(2)));

#define E_DIM 1024
#define HD 64
#define NH 16
#define LOG2E 1.44269504088896f

__device__ __forceinline__ float toF(float x) { return x; }
__device__ __forceinline__ float toF(__hip_bfloat16 x) { return __bfloat162float(x); }
__device__ __forceinline__ void storeOut(float* p, float v) { *p = v; }
__device__ __forceinline__ void storeOut(__hip_bfloat16* p, float v) { *p = __float2bfloat16(v); }

__device__ __forceinline__ unsigned cvtpk_bf16(float lo, float hi_) {
    unsigned r;
    asm("v_cvt_pk_bf16_f32 %0, %1, %2" : "=v"(r) : "v"(lo), "v"(hi_));
    return r;
}
__device__ __forceinline__ void perm32swap(unsigned& a, unsigned& b) {
    uint2v r = __builtin_amdgcn_permlane32_swap(a, b, false, false);
    a = r.x; b = r.y;
}

// ---------------- cast fp32 -> bf16 (vectorized) ----------------
__global__ void cast_f32_bf16_kernel(const float* __restrict__ in, __hip_bfloat16* __restrict__ o, int n) {
    int i = (blockIdx.x * blockDim.x + threadIdx.x) * 4;
    if (i + 3 < n) {
        float4 v = *reinterpret_cast<const float4*>(in + i);
        __hip_bfloat16 t[4] = {__float2bfloat16(v.x), __float2bfloat16(v.y),
                               __float2bfloat16(v.z), __float2bfloat16(v.w)};
        *reinterpret_cast<uint2*>(o + i) = *reinterpret_cast<uint2*>(t);
    }
}

// ---------------- tiled cast-transpose: out[c][r] = in[r][c] ----------------
template<typename InT>
__global__ void transpose_cast_kernel(const InT* __restrict__ in, int ldi,
                                      __hip_bfloat16* __restrict__ out, int ldo,
                                      int R, int C) {
    __shared__ float tile[32][33];
    const int bx = blockIdx.x * 32;  // r
    const int by = blockIdx.y * 32;  // c
    const int tx = threadIdx.x & 31, ty = threadIdx.x >> 5;  // 32 x 8
#pragma unroll
    for (int j = 0; j < 4; ++j) {
        int r = bx + ty + j * 8, c = by + tx;
        tile[ty + j * 8][tx] = toF(in[(size_t)r * ldi + c]);
    }
    __syncthreads();
#pragma unroll
    for (int j = 0; j < 4; ++j) {
        int c = by + ty + j * 8, r = bx + tx;
        out[(size_t)c * ldo + r] = __float2bfloat16(tile[tx][ty + j * 8]);
    }
}

// ---------------- concat bk|bv ----------------
__global__ void concat_bias_kernel(const float* __restrict__ bk, const float* __restrict__ bv,
                                   float* __restrict__ bkv) {
    int i = threadIdx.x;  // 128 threads
    bkv[i] = (i < HD) ? bk[i] : bv[i - HD];
}

// ---------------- mask -> 64-bit words via ballot ----------------
__global__ void maskbits_kernel(const int* __restrict__ mask, unsigned long long* __restrict__ mb,
                                int nwords) {
    int gtid = blockIdx.x * blockDim.x + threadIdx.x;
    int wid = gtid >> 6, lane = gtid & 63;
    int nw = (gridDim.x * blockDim.x) >> 6;
    for (int w = wid; w < nwords; w += nw) {
        int v = mask[(size_t)w * 64 + lane];
        unsigned long long b = __ballot(v != 0);
        if (lane == 0) mb[w] = b;
    }
}

// ---------------- bf16 GEMM: C[M][N] = A[M][K] * Bt[N][K]^T, epilogue (acc+bias)*scale ----------------
template<typename OutT>
__global__ __launch_bounds__(256)
void gemm_bt_kernel(const __hip_bfloat16* __restrict__ A,
                    const __hip_bfloat16* __restrict__ Bt,
                    const float* __restrict__ bias,
                    OutT* __restrict__ C,
                    int M, int N, int K, float scale) {
    constexpr int BM = 128, BN = 128, BK = 32;
    __shared__ __align__(16) unsigned char lA[BM * BK * 2];  // [row][64B] swizzled
    __shared__ __align__(16) unsigned char lB[BN * BK * 2];
    const int ntn = N / BN;
    const int tm = blockIdx.x / ntn, tn = blockIdx.x % ntn;
    const int tid = threadIdx.x, lane = tid & 63, wave = tid >> 6;
    const int l15 = lane & 15, l4 = lane >> 4;
    const int wm = (wave >> 1) * 64, wn = (wave & 1) * 64;
    const int r0 = tm * BM, c0 = tn * BN;
    f32x4 z4 = {0.f, 0.f, 0.f, 0.f};
    f32x4 acc[4][4];
#pragma unroll
    for (int mi = 0; mi < 4; ++mi)
#pragma unroll
        for (int ni = 0; ni < 4; ++ni) acc[mi][ni] = z4;

    for (int k0 = 0; k0 < K; k0 += BK) {
#pragma unroll
        for (int i = 0; i < 2; ++i) {
            int id = tid + i * 256;        // 0..511 : 16B chunks
            int row = id >> 2;             // 0..127
            int cb = (id & 3) * 16;        // byte in 64B row
            int sw = cb ^ ((row & 3) << 4);
            uint4 va = *reinterpret_cast<const uint4*>(
                reinterpret_cast<const unsigned char*>(A + (size_t)(r0 + row) * K + k0) + cb);
            *reinterpret_cast<uint4*>(&lA[row * 64 + sw]) = va;
            uint4 vb = *reinterpret_cast<const uint4*>(
                reinterpret_cast<const unsigned char*>(Bt + (size_t)(c0 + row) * K + k0) + cb);
            *reinterpret_cast<uint4*>(&lB[row * 64 + sw]) = vb;
        }
        __syncthreads();
        bf16x8 af[4], bf[4];
#pragma unroll
        for (int mi = 0; mi < 4; ++mi) {
            int row = wm + mi * 16 + l15;
            af[mi] = *reinterpret_cast<const bf16x8*>(&lA[row * 64 + ((l4 * 16) ^ ((row & 3) << 4))]);
        }
#pragma unroll
        for (int ni = 0; ni < 4; ++ni) {
            int row = wn + ni * 16 + l15;
            bf[ni] = *reinterpret_cast<const bf16x8*>(&lB[row * 64 + ((l4 * 16) ^ ((row & 3) << 4))]);
        }
#pragma unroll
        for (int mi = 0; mi < 4; ++mi)
#pragma unroll
            for (int ni = 0; ni < 4; ++ni)
                acc[mi][ni] = __builtin_amdgcn_mfma_f32_16x16x32_bf16(af[mi], bf[ni], acc[mi][ni], 0, 0, 0);
        __syncthreads();
    }
#pragma unroll
    for (int ni = 0; ni < 4; ++ni) {
        int col = c0 + wn + ni * 16 + l15;
        float b = bias[col];
#pragma unroll
        for (int mi = 0; mi < 4; ++mi) {
            int row = r0 + wm + mi * 16 + l4 * 4;
#pragma unroll
            for (int r = 0; r < 4; ++r) {
                float v = (acc[mi][ni][r] + b) * scale;
                storeOut(C + (size_t)(row + r) * N + col, v);
            }
        }
    }
}

// ---------------- MQA flash attention v2 ----------------
// 8 waves/block; wave = one head, 32 q-rows. Swapped QK^T (lane-local q), Oᵀ PV.
// LDS rows: [tile_row r][256B] = K[k=r][0:64] (chunks 0..7) | Vt[d=r][k-tile] (chunks 8..15),
// chunk swizzle: slot = chunk ^ (r & 15).
__global__ __launch_bounds__(512, 2)
void mqa2_kernel(const __hip_bfloat16* __restrict__ qb,
                 const __hip_bfloat16* __restrict__ kvb,
                 const __hip_bfloat16* __restrict__ vtb,
                 const unsigned long long* __restrict__ mbits,
                 __hip_bfloat16* __restrict__ attnb,
                 int S) {
    __shared__ __align__(16) unsigned char sKV[2][64 * 256];
    const int tid = threadIdx.x, lane = tid & 63, w = tid >> 6;
    const int r31 = lane & 31, hi = lane >> 5;
    const int q0 = blockIdx.x * 32;
    const int h = blockIdx.y * 8 + w;
    const int NT = S / 64, nw64 = S / 64;

    // Q fragments (prescaled by 1/8 in the q GEMM): qf[s] = Q[q0+r31][h*64 + hi*8 + 16s + 0..7]
    bf16x8 qf[4];
    {
        const __hip_bfloat16* qp = qb + (size_t)(q0 + r31) * E_DIM + h * HD + hi * 8;
#pragma unroll
        for (int s = 0; s < 4; ++s) qf[s] = *reinterpret_cast<const bf16x8*>(qp + 16 * s);
    }

    // staging: wave w owns tile rows [w*8, w*8+8); lane -> (row, chunk)
    const int sch = lane & 15;
    const __hip_bfloat16* gsrc[2];
    size_t gstep[2];     // elements per tile
    unsigned ldst[2];    // swizzled LDS byte offset
#pragma unroll
    for (int ia = 0; ia < 2; ++ia) {
        int r = w * 8 + ia * 4 + (lane >> 4);
        if (sch < 8) { gsrc[ia] = kvb + (size_t)r * 128 + sch * 8; gstep[ia] = 64 * 128; }
        else         { gsrc[ia] = vtb + (size_t)r * S + (sch - 8) * 8; gstep[ia] = 64; }
        ldst[ia] = r * 256 + ((sch ^ (r & 15)) * 16);
    }

    uint4 rcur[2], rnext[2];
#pragma unroll
    for (int ia = 0; ia < 2; ++ia) rcur[ia] = *reinterpret_cast<const uint4*>(gsrc[ia]);
#pragma unroll
    for (int ia = 0; ia < 2; ++ia) rnext[ia] = *reinterpret_cast<const uint4*>(gsrc[ia] + gstep[ia]);
    __syncthreads();  // drain loads
#pragma unroll
    for (int ia = 0; ia < 2; ++ia) *reinterpret_cast<uint4*>(&sKV[0][ldst[ia]]) = rcur[ia];
    rcur[0] = rnext[0]; rcur[1] = rnext[1];
    __syncthreads();  // buf0 visible; invariant: buf[cur]=tile t, rcur=tile t+1

    float rm = -3e38f, rl = 0.f;
    f32x16 oacc[2];
#pragma unroll
    for (int i = 0; i < 16; ++i) { oacc[0][i] = 0.f; oacc[1][i] = 0.f; }

    int cur = 0;
    for (int t = 0; t < NT; ++t) {
        // issue tile t+2 loads (hidden under compute; drained by end-of-iter barrier)
        if (t + 2 < NT) {
#pragma unroll
            for (int ia = 0; ia < 2; ++ia)
                rnext[ia] = *reinterpret_cast<const uint4*>(gsrc[ia] + (size_t)(t + 2) * gstep[ia]);
        }
        unsigned long long wb = mbits[(size_t)(q0 + r31) * nw64 + t];
        const unsigned char* buf = sKV[cur];
        const int rx = r31 & 15;

        // ---- QK^T: sacc[kb][reg] = S[k = kb*32 + crow(reg,hi)][q = r31]
        f32x16 sacc[2];
#pragma unroll
        for (int kb = 0; kb < 2; ++kb) {
            const unsigned char* rowp = buf + (kb * 32 + r31) * 256;
            f32x16 a;
#pragma unroll
            for (int i = 0; i < 16; ++i) a[i] = 0.f;
#pragma unroll
            for (int s = 0; s < 4; ++s) {
                int slot = (2 * s + hi) ^ rx;
                bf16x8 kf = *reinterpret_cast<const bf16x8*>(rowp + slot * 16);
                a = __builtin_amdgcn_mfma_f32_32x32x16_bf16(kf, qf[s], a, 0, 0, 0);
            }
            sacc[kb] = a;
        }

        // ---- mask (free when all-ones)
        if (wb != ~0ull) {
#pragma unroll
            for (int r = 0; r < 16; ++r) {
                int kl = (r & 3) + 8 * (r >> 2) + 4 * hi;
                if (!((wb >> kl) & 1)) sacc[0][r] = -10000.f;
                if (!((wb >> (kl + 32)) & 1)) sacc[1][r] = -10000.f;
            }
        }

        // ---- online softmax (q lane-local; one cross-lane exchange with lane^32)
        float pmax = -3e38f;
#pragma unroll
        for (int r = 0; r < 16; ++r) pmax = fmaxf(pmax, fmaxf(sacc[0][r], sacc[1][r]));
        pmax = fmaxf(pmax, __shfl_xor(pmax, 32));
        float rmn = fmaxf(rm, pmax);
        float al = exp2f((rm - rmn) * LOG2E);
        float nf = -rmn * LOG2E;
        float sum = 0.f;
#pragma unroll
        for (int r = 0; r < 16; ++r) {
            float p0 = exp2f(fmaf(sacc[0][r], LOG2E, nf));
            float p1 = exp2f(fmaf(sacc[1][r], LOG2E, nf));
            sacc[0][r] = p0; sacc[1][r] = p1;
            sum += p0 + p1;
        }
        sum += __shfl_xor(sum, 32);
        rl = rl * al + sum;
        rm = rmn;
#pragma unroll
        for (int r = 0; r < 16; ++r) { oacc[0][r] *= al; oacc[1][r] *= al; }

        // ---- P -> bf16 A-frags: pa[s] holds P[q=r31][k = 16s + hi*8 + j]
        bf16x8 pa[4];
#pragma unroll
        for (int kb = 0; kb < 2; ++kb) {
#pragma unroll
            for (int half = 0; half < 2; ++half) {
                int b0 = half * 8;
                unsigned A = cvtpk_bf16(sacc[kb][b0 + 0], sacc[kb][b0 + 1]);
                unsigned B = cvtpk_bf16(sacc[kb][b0 + 2], sacc[kb][b0 + 3]);
                unsigned C = cvtpk_bf16(sacc[kb][b0 + 4], sacc[kb][b0 + 5]);
                unsigned D = cvtpk_bf16(sacc[kb][b0 + 6], sacc[kb][b0 + 7]);
                perm32swap(A, C);
                perm32swap(B, D);
                union { unsigned u[4]; bf16x8 v; } pk;
                pk.u[0] = A; pk.u[1] = B; pk.u[2] = C; pk.u[3] = D;
                pa[kb * 2 + half] = pk.v;
            }
        }

        // ---- PV (Oᵀ): oacc[db] += Vt-frag * Pᵀ ; lane holds O[q=r31][d = db*32 + crow(reg,hi)]
#pragma unroll
        for (int db = 0; db < 2; ++db) {
            const unsigned char* rowp = buf + (db * 32 + r31) * 256;
            f32x16 a = oacc[db];
#pragma unroll
            for (int s = 0; s < 4; ++s) {
                int slot = (8 + 2 * s + hi) ^ rx;
                bf16x8 vf = *reinterpret_cast<const bf16x8*>(rowp + slot * 16);
                a = __builtin_amdgcn_mfma_f32_32x32x16_bf16(vf, pa[s], a, 0, 0, 0);
            }
            oacc[db] = a;
        }

        // ---- write tile t+1 into the other buffer, rotate
        if (t + 1 < NT) {
#pragma unroll
            for (int ia = 0; ia < 2; ++ia) *reinterpret_cast<uint4*>(&sKV[cur ^ 1][ldst[ia]]) = rcur[ia];
        }
        rcur[0] = rnext[0]; rcur[1] = rnext[1];
        __syncthreads();
        cur ^= 1;
    }

    // ---- epilogue: O /= l ; d = db*32 + 8m + 4hi + i
    float inv = 1.0f / rl;
    __hip_bfloat16* op = attnb + (size_t)(q0 + r31) * E_DIM + h * HD;
#pragma unroll
    for (int db = 0; db < 2; ++db)
#pragma unroll
        for (int m = 0; m < 4; ++m) {
            uint2 pk;
            pk.x = cvtpk_bf16(oacc[db][4 * m + 0] * inv, oacc[db][4 * m + 1] * inv);
            pk.y = cvtpk_bf16(oacc[db][4 * m + 2] * inv, oacc[db][4 * m + 3] * inv);
            *reinterpret_cast<uint2*>(op + db * 32 + m * 8 + hi * 4) = pk;
        }
}

// ---------------- host launch ----------------
extern "C" void kernel_launch(void* const* d_in, const int* in_sizes, int n_in,
                              void* d_out, int out_size, void* d_ws, size_t ws_size,
                              hipStream_t stream) {
    (void)n_in; (void)out_size; (void)ws_size;
    const float* x  = (const float*)d_in[0];
    const int* mask = (const int*)d_in[1];
    const float* Wq = (const float*)d_in[2];
    const float* bq = (const float*)d_in[3];
    const float* Wk = (const float*)d_in[4];
    const float* bk = (const float*)d_in[5];
    const float* Wv = (const float*)d_in[6];
    const float* bv = (const float*)d_in[7];
    const float* Wo = (const float*)d_in[8];
    const float* bo = (const float*)d_in[9];
    float* out = (float*)d_out;

    const int E = E_DIM;
    const int S = in_sizes[0] / E;

    char* ws = (char*)d_ws;
    size_t off = 0;
    auto alloc = [&](size_t b) { char* p = ws + off; off += (b + 255) & ~(size_t)255; return p; };
    __hip_bfloat16* xb    = (__hip_bfloat16*)alloc((size_t)S * E * 2);
    __hip_bfloat16* wqT   = (__hip_bfloat16*)alloc((size_t)E * E * 2);
    __hip_bfloat16* wkvT  = (__hip_bfloat16*)alloc((size_t)128 * E * 2);
    __hip_bfloat16* woT   = (__hip_bfloat16*)alloc((size_t)E * E * 2);
    __hip_bfloat16* qb    = (__hip_bfloat16*)alloc((size_t)S * E * 2);
    __hip_bfloat16* kvb   = (__hip_bfloat16*)alloc((size_t)S * 128 * 2);
    __hip_bfloat16* vtb   = (__hip_bfloat16*)alloc((size_t)HD * S * 2);
    __hip_bfloat16* attnb = (__hip_bfloat16*)alloc((size_t)S * E * 2);
    float* bkv = (float*)alloc(512);
    unsigned long long* mbits = (unsigned long long*)alloc((size_t)S * (S / 64) * 8);

    cast_f32_bf16_kernel<<<dim3((S * E / 4 + 255) / 256), dim3(256), 0, stream>>>(x, xb, S * E);
    transpose_cast_kernel<float><<<dim3(E / 32, E / 32), dim3(256), 0, stream>>>(Wq, E, wqT, E, E, E);
    transpose_cast_kernel<float><<<dim3(E / 32, HD / 32), dim3(256), 0, stream>>>(Wk, HD, wkvT, E, E, HD);
    transpose_cast_kernel<float><<<dim3(E / 32, HD / 32), dim3(256), 0, stream>>>(Wv, HD, wkvT + (size_t)HD * E, E, E, HD);
    transpose_cast_kernel<float><<<dim3(E / 32, E / 32), dim3(256), 0, stream>>>(Wo, E, woT, E, E, E);
    concat_bias_kernel<<<dim3(1), dim3(128), 0, stream>>>(bk, bv, bkv);
    maskbits_kernel<<<dim3(1024), dim3(256), 0, stream>>>(mask, mbits, S * (S / 64));

    // q = (x @ Wq + bq) * 1/sqrt(64)   -> bf16 [S][1024]
    gemm_bt_kernel<__hip_bfloat16><<<dim3((S / 128) * (E / 128)), dim3(256), 0, stream>>>(
        xb, wqT, bq, qb, S, E, E, 0.125f);
    // kv = x @ [Wk|Wv] + [bk|bv]       -> bf16 [S][128]
    gemm_bt_kernel<__hip_bfloat16><<<dim3(S / 128), dim3(256), 0, stream>>>(
        xb, wkvT, bkv, kvb, S, 128, E, 1.0f);
    // v^T [64][S]
    transpose_cast_kernel<__hip_bfloat16><<<dim3(S / 32, HD / 32), dim3(256), 0, stream>>>(
        kvb + HD, 128, vtb, S, S, HD);
    // attention (merged-head MQA, swapped-QK^T flash)
    mqa2_kernel<<<dim3(S / 32, 2), dim3(512), 0, stream>>>(qb, kvb, vtb, mbits, attnb, S);
    // out = attn @ Wo + bo  (fp32)
    gemm_bt_kernel<float><<<dim3((S / 128) * (E / 128)), dim3(256), 0, stream>>>(
        attnb, woT, bo, out, S, E, E, 1.0f);
}

// Round 3
// 239.002 us; speedup vs baseline: 1.6004x; 1.3491x over previous
//
#include <hip/hip_runtime.h>
#include <hip/hip_bf16.h>
#include <stdint.h>

typedef __bf16 bf16x8 __attribute__((ext_vector_type(8)));
typedef float f32x4 __attribute__((ext_vector_type(4)));
typedef float f32x16 __attribute__((ext_vector_type(16)));
typedef unsigned int uint2v __attribute__((ext_vector_type(2)));

#define E_DIM 1024
#define HD 64
#define NH 16
#define LOG2E 1.44269504088896f

__device__ __forceinline__ float toF(float x) { return x; }
__device__ __forceinline__ float toF(__hip_bfloat16 x) { return __bfloat162float(x); }
__device__ __forceinline__ void storeOut(float* p, float v) { *p = v; }
__device__ __forceinline__ void storeOut(__hip_bfloat16* p, float v) { *p = __float2bfloat16(v); }

__device__ __forceinline__ unsigned cvtpk_bf16(float lo, float hi_) {
    unsigned r;
    asm("v_cvt_pk_bf16_f32 %0, %1, %2" : "=v"(r) : "v"(lo), "v"(hi_));
    return r;
}
__device__ __forceinline__ void perm32swap(unsigned& a, unsigned& b) {
    uint2v r = __builtin_amdgcn_permlane32_swap(a, b, false, false);
    a = r.x; b = r.y;
}
__device__ __forceinline__ float fexp2(float x) {
    float r;
    asm("v_exp_f32 %0, %1" : "=v"(r) : "v"(x));
    return r;
}

typedef __attribute__((address_space(1))) void gvoid;
typedef __attribute__((address_space(3))) void lvoid;
__device__ __forceinline__ void gload_lds16(const void* g, void* l) {
    __builtin_amdgcn_global_load_lds((gvoid*)g, (lvoid*)l, 16, 0, 0);
}

// ---------------- cast fp32 -> bf16 (vectorized) ----------------
__global__ void cast_f32_bf16_kernel(const float* __restrict__ in, __hip_bfloat16* __restrict__ o, int n) {
    int i = (blockIdx.x * blockDim.x + threadIdx.x) * 4;
    if (i + 3 < n) {
        float4 v = *reinterpret_cast<const float4*>(in + i);
        __hip_bfloat16 t[4] = {__float2bfloat16(v.x), __float2bfloat16(v.y),
                               __float2bfloat16(v.z), __float2bfloat16(v.w)};
        *reinterpret_cast<uint2*>(o + i) = *reinterpret_cast<uint2*>(t);
    }
}

// ---------------- tiled cast-transpose: out[c][r] = in[r][c] ----------------
template<typename InT>
__global__ void transpose_cast_kernel(const InT* __restrict__ in, int ldi,
                                      __hip_bfloat16* __restrict__ out, int ldo,
                                      int R, int C) {
    __shared__ float tile[32][33];
    const int bx = blockIdx.x * 32;  // r
    const int by = blockIdx.y * 32;  // c
    const int tx = threadIdx.x & 31, ty = threadIdx.x >> 5;  // 32 x 8
#pragma unroll
    for (int j = 0; j < 4; ++j) {
        int r = bx + ty + j * 8, c = by + tx;
        tile[ty + j * 8][tx] = toF(in[(size_t)r * ldi + c]);
    }
    __syncthreads();
#pragma unroll
    for (int j = 0; j < 4; ++j) {
        int c = by + ty + j * 8, r = bx + tx;
        out[(size_t)c * ldo + r] = __float2bfloat16(tile[tx][ty + j * 8]);
    }
}

// ---------------- concat bk|bv ----------------
__global__ void concat_bias_kernel(const float* __restrict__ bk, const float* __restrict__ bv,
                                   float* __restrict__ bkv) {
    int i = threadIdx.x;  // 128 threads
    bkv[i] = (i < HD) ? bk[i] : bv[i - HD];
}

// ---------------- mask -> 64-bit words via ballot ----------------
__global__ void maskbits_kernel(const int* __restrict__ mask, unsigned long long* __restrict__ mb,
                                int nwords) {
    int gtid = blockIdx.x * blockDim.x + threadIdx.x;
    int wid = gtid >> 6, lane = gtid & 63;
    int nw = (gridDim.x * blockDim.x) >> 6;
    for (int w = wid; w < nwords; w += nw) {
        int v = mask[(size_t)w * 64 + lane];
        unsigned long long b = __ballot(v != 0);
        if (lane == 0) mb[w] = b;
    }
}

// ---------------- bf16 GEMM: C[M][N] = A[M][K] * Bt[N][K]^T, epilogue (acc+bias)*scale ----------------
template<typename OutT>
__global__ __launch_bounds__(256)
void gemm_bt_kernel(const __hip_bfloat16* __restrict__ A,
                    const __hip_bfloat16* __restrict__ Bt,
                    const float* __restrict__ bias,
                    OutT* __restrict__ C,
                    int M, int N, int K, float scale) {
    constexpr int BM = 128, BN = 128, BK = 32;
    __shared__ __align__(16) unsigned char lA[BM * BK * 2];  // [row][64B] swizzled
    __shared__ __align__(16) unsigned char lB[BN * BK * 2];
    const int ntn = N / BN;
    const int tm = blockIdx.x / ntn, tn = blockIdx.x % ntn;
    const int tid = threadIdx.x, lane = tid & 63, wave = tid >> 6;
    const int l15 = lane & 15, l4 = lane >> 4;
    const int wm = (wave >> 1) * 64, wn = (wave & 1) * 64;
    const int r0 = tm * BM, c0 = tn * BN;
    f32x4 z4 = {0.f, 0.f, 0.f, 0.f};
    f32x4 acc[4][4];
#pragma unroll
    for (int mi = 0; mi < 4; ++mi)
#pragma unroll
        for (int ni = 0; ni < 4; ++ni) acc[mi][ni] = z4;

    for (int k0 = 0; k0 < K; k0 += BK) {
#pragma unroll
        for (int i = 0; i < 2; ++i) {
            int id = tid + i * 256;        // 0..511 : 16B chunks
            int row = id >> 2;             // 0..127
            int cb = (id & 3) * 16;        // byte in 64B row
            int sw = cb ^ ((row & 3) << 4);
            uint4 va = *reinterpret_cast<const uint4*>(
                reinterpret_cast<const unsigned char*>(A + (size_t)(r0 + row) * K + k0) + cb);
            *reinterpret_cast<uint4*>(&lA[row * 64 + sw]) = va;
            uint4 vb = *reinterpret_cast<const uint4*>(
                reinterpret_cast<const unsigned char*>(Bt + (size_t)(c0 + row) * K + k0) + cb);
            *reinterpret_cast<uint4*>(&lB[row * 64 + sw]) = vb;
        }
        __syncthreads();
        bf16x8 af[4], bf[4];
#pragma unroll
        for (int mi = 0; mi < 4; ++mi) {
            int row = wm + mi * 16 + l15;
            af[mi] = *reinterpret_cast<const bf16x8*>(&lA[row * 64 + ((l4 * 16) ^ ((row & 3) << 4))]);
        }
#pragma unroll
        for (int ni = 0; ni < 4; ++ni) {
            int row = wn + ni * 16 + l15;
            bf[ni] = *reinterpret_cast<const bf16x8*>(&lB[row * 64 + ((l4 * 16) ^ ((row & 3) << 4))]);
        }
#pragma unroll
        for (int mi = 0; mi < 4; ++mi)
#pragma unroll
            for (int ni = 0; ni < 4; ++ni)
                acc[mi][ni] = __builtin_amdgcn_mfma_f32_16x16x32_bf16(af[mi], bf[ni], acc[mi][ni], 0, 0, 0);
        __syncthreads();
    }
#pragma unroll
    for (int ni = 0; ni < 4; ++ni) {
        int col = c0 + wn + ni * 16 + l15;
        float b = bias[col];
#pragma unroll
        for (int mi = 0; mi < 4; ++mi) {
            int row = r0 + wm + mi * 16 + l4 * 4;
#pragma unroll
            for (int r = 0; r < 4; ++r) {
                float v = (acc[mi][ni][r] + b) * scale;
                storeOut(C + (size_t)(row + r) * N + col, v);
            }
        }
    }
}

// ---------------- MQA flash attention v3 ----------------
// 4 waves/block (wave = head), 32 q-rows/block. Swapped QK^T (q lane-local), Oᵀ PV.
// Staging via global_load_lds with pre-swizzled global source; log2-domain softmax;
// defer-max rescale. LDS tile: row r (64 rows, 256B): K[k0+r][0:64] chunks 0..7,
// Vt[d=r][k0+..] chunks 8..15; chunk c stored at slot c ^ (r&15).
__global__ __launch_bounds__(256, 3)
void mqa3_kernel(const __hip_bfloat16* __restrict__ qb,
                 const __hip_bfloat16* __restrict__ kvb,
                 const __hip_bfloat16* __restrict__ vtb,
                 const unsigned long long* __restrict__ mbits,
                 __hip_bfloat16* __restrict__ attnb,
                 int S) {
    __shared__ __align__(16) unsigned char sKV[2][16384];
    const int tid = threadIdx.x, lane = tid & 63, w = tid >> 6;
    const int r31 = lane & 31, hi = lane >> 5, rx = r31 & 15;
    const int q0 = blockIdx.x * 32;
    const int h = blockIdx.y * 4 + w;
    const int NT = S / 64;

    // Q fragments (prescaled by 0.125*log2e in the q GEMM)
    bf16x8 qf[4];
    {
        const __hip_bfloat16* qp = qb + (size_t)(q0 + r31) * E_DIM + h * HD + hi * 8;
#pragma unroll
        for (int s = 0; s < 4; ++s) qf[s] = *reinterpret_cast<const bf16x8*>(qp + 16 * s);
    }

    // staging: wave w owns tile rows [w*16, w*16+16) -> 4 x 1KB global_load_lds_dwordx4
    const char* gbase[4];
    int gstep[4];
    unsigned ldsoff[4];
#pragma unroll
    for (int i = 0; i < 4; ++i) {
        int r = w * 16 + i * 4 + (lane >> 4);
        int sl = lane & 15;            // LDS 16B slot
        int c = sl ^ (r & 15);         // global chunk that lands in this slot
        if (c < 8) { gbase[i] = (const char*)(kvb + (size_t)r * 128 + c * 8); gstep[i] = 64 * 256; }
        else       { gbase[i] = (const char*)(vtb + (size_t)r * S + (c - 8) * 8); gstep[i] = 128; }
        ldsoff[i] = w * 4096 + i * 1024;
    }

    // prologue: stage tile 0
#pragma unroll
    for (int i = 0; i < 4; ++i) { gload_lds16(gbase[i], &sKV[0][ldsoff[i]]); gbase[i] += gstep[i]; }
    __syncthreads();

    float rm = -3e38f, rl = 0.f;
    f32x16 oacc[2];
#pragma unroll
    for (int i = 0; i < 16; ++i) { oacc[0][i] = 0.f; oacc[1][i] = 0.f; }

    int buf = 0;
    for (int t = 0; t < NT; ++t) {
        // stage tile t+1 into other buffer (drained by end-of-iter barrier)
        if (t + 1 < NT) {
#pragma unroll
            for (int i = 0; i < 4; ++i) { gload_lds16(gbase[i], &sKV[buf ^ 1][ldsoff[i]]); gbase[i] += gstep[i]; }
        }
        unsigned long long wb = mbits[(size_t)(q0 + r31) * NT + t];
        const unsigned char* bp = sKV[buf];

        // ---- QK^T: sacc[kb][reg] = S_log2[k = kb*32 + crow(reg,hi)][q = r31]
        f32x16 sacc[2];
#pragma unroll
        for (int kb = 0; kb < 2; ++kb) {
            const unsigned char* rowp = bp + (kb * 32 + r31) * 256;
            f32x16 a;
#pragma unroll
            for (int i = 0; i < 16; ++i) a[i] = 0.f;
#pragma unroll
            for (int s = 0; s < 4; ++s) {
                int slot = (2 * s + hi) ^ rx;
                bf16x8 kf = *reinterpret_cast<const bf16x8*>(rowp + slot * 16);
                a = __builtin_amdgcn_mfma_f32_32x32x16_bf16(kf, qf[s], a, 0, 0, 0);
            }
            sacc[kb] = a;
        }

        // ---- mask (free when all-ones); -10000 * log2e
        if (wb != ~0ull) {
#pragma unroll
            for (int r = 0; r < 16; ++r) {
                int kl = (r & 3) + 8 * (r >> 2) + 4 * hi;
                if (!((wb >> kl) & 1)) sacc[0][r] = -14427.0f;
                if (!((wb >> (kl + 32)) & 1)) sacc[1][r] = -14427.0f;
            }
        }

        // ---- tile max (ILP tree) + one cross-half exchange
        float t0[8];
#pragma unroll
        for (int j = 0; j < 8; ++j)
            t0[j] = fmaxf(fmaxf(sacc[0][j], sacc[0][j + 8]), fmaxf(sacc[1][j], sacc[1][j + 8]));
        float u0 = fmaxf(t0[0], t0[4]), u1 = fmaxf(t0[1], t0[5]);
        float u2 = fmaxf(t0[2], t0[6]), u3 = fmaxf(t0[3], t0[7]);
        float pmax = fmaxf(fmaxf(u0, u1), fmaxf(u2, u3));
        pmax = fmaxf(pmax, __shfl_xor(pmax, 32));

        // ---- defer-max: rescale only when needed (wave-uniform branch)
        if (!__all(pmax - rm <= 8.0f)) {
            float rmn = fmaxf(rm, pmax);
            float al = fexp2(rm - rmn);
            rl *= al;
#pragma unroll
            for (int r = 0; r < 16; ++r) { oacc[0][r] *= al; oacc[1][r] *= al; }
            rm = rmn;
        }

        // ---- p = exp2(s - rm), 4-way partial sums
        float s0 = 0.f, s1 = 0.f, s2 = 0.f, s3 = 0.f;
#pragma unroll
        for (int r = 0; r < 16; r += 4) {
            sacc[0][r + 0] = fexp2(sacc[0][r + 0] - rm); s0 += sacc[0][r + 0];
            sacc[0][r + 1] = fexp2(sacc[0][r + 1] - rm); s1 += sacc[0][r + 1];
            sacc[0][r + 2] = fexp2(sacc[0][r + 2] - rm); s2 += sacc[0][r + 2];
            sacc[0][r + 3] = fexp2(sacc[0][r + 3] - rm); s3 += sacc[0][r + 3];
        }
#pragma unroll
        for (int r = 0; r < 16; r += 4) {
            sacc[1][r + 0] = fexp2(sacc[1][r + 0] - rm); s0 += sacc[1][r + 0];
            sacc[1][r + 1] = fexp2(sacc[1][r + 1] - rm); s1 += sacc[1][r + 1];
            sacc[1][r + 2] = fexp2(sacc[1][r + 2] - rm); s2 += sacc[1][r + 2];
            sacc[1][r + 3] = fexp2(sacc[1][r + 3] - rm); s3 += sacc[1][r + 3];
        }
        float sum = (s0 + s1) + (s2 + s3);
        sum += __shfl_xor(sum, 32);
        rl += sum;

        // ---- P -> bf16 A-frags: pa[s] holds P[q=r31][k = 16s + hi*8 + j]
        bf16x8 pa[4];
#pragma unroll
        for (int kb = 0; kb < 2; ++kb) {
#pragma unroll
            for (int half = 0; half < 2; ++half) {
                int b0 = half * 8;
                unsigned A = cvtpk_bf16(sacc[kb][b0 + 0], sacc[kb][b0 + 1]);
                unsigned B = cvtpk_bf16(sacc[kb][b0 + 2], sacc[kb][b0 + 3]);
                unsigned C = cvtpk_bf16(sacc[kb][b0 + 4], sacc[kb][b0 + 5]);
                unsigned D = cvtpk_bf16(sacc[kb][b0 + 6], sacc[kb][b0 + 7]);
                perm32swap(A, C);
                perm32swap(B, D);
                union { unsigned u[4]; bf16x8 v; } pk;
                pk.u[0] = A; pk.u[1] = B; pk.u[2] = C; pk.u[3] = D;
                pa[kb * 2 + half] = pk.v;
            }
        }

        // ---- PV (Oᵀ): oacc[db] += Vt-frag * Pᵀ
#pragma unroll
        for (int db = 0; db < 2; ++db) {
            const unsigned char* rowp = bp + (db * 32 + r31) * 256;
            f32x16 a = oacc[db];
#pragma unroll
            for (int s = 0; s < 4; ++s) {
                int slot = (8 + 2 * s + hi) ^ rx;
                bf16x8 vf = *reinterpret_cast<const bf16x8*>(rowp + slot * 16);
                a = __builtin_amdgcn_mfma_f32_32x32x16_bf16(vf, pa[s], a, 0, 0, 0);
            }
            oacc[db] = a;
        }

        __syncthreads();
        buf ^= 1;
    }

    // ---- epilogue: O /= l ; d = db*32 + 8m + 4hi + i
    float inv = 1.0f / rl;
    __hip_bfloat16* op = attnb + (size_t)(q0 + r31) * E_DIM + h * HD;
#pragma unroll
    for (int db = 0; db < 2; ++db)
#pragma unroll
        for (int m = 0; m < 4; ++m) {
            uint2 pk;
            pk.x = cvtpk_bf16(oacc[db][4 * m + 0] * inv, oacc[db][4 * m + 1] * inv);
            pk.y = cvtpk_bf16(oacc[db][4 * m + 2] * inv, oacc[db][4 * m + 3] * inv);
            *reinterpret_cast<uint2*>(op + db * 32 + m * 8 + hi * 4) = pk;
        }
}

// ---------------- host launch ----------------
extern "C" void kernel_launch(void* const* d_in, const int* in_sizes, int n_in,
                              void* d_out, int out_size, void* d_ws, size_t ws_size,
                              hipStream_t stream) {
    (void)n_in; (void)out_size; (void)ws_size;
    const float* x  = (const float*)d_in[0];
    const int* mask = (const int*)d_in[1];
    const float* Wq = (const float*)d_in[2];
    const float* bq = (const float*)d_in[3];
    const float* Wk = (const float*)d_in[4];
    const float* bk = (const float*)d_in[5];
    const float* Wv = (const float*)d_in[6];
    const float* bv = (const float*)d_in[7];
    const float* Wo = (const float*)d_in[8];
    const float* bo = (const float*)d_in[9];
    float* out = (float*)d_out;

    const int E = E_DIM;
    const int S = in_sizes[0] / E;

    char* ws = (char*)d_ws;
    size_t off = 0;
    auto alloc = [&](size_t b) { char* p = ws + off; off += (b + 255) & ~(size_t)255; return p; };
    __hip_bfloat16* xb    = (__hip_bfloat16*)alloc((size_t)S * E * 2);
    __hip_bfloat16* wqT   = (__hip_bfloat16*)alloc((size_t)E * E * 2);
    __hip_bfloat16* wkvT  = (__hip_bfloat16*)alloc((size_t)128 * E * 2);
    __hip_bfloat16* woT   = (__hip_bfloat16*)alloc((size_t)E * E * 2);
    __hip_bfloat16* qb    = (__hip_bfloat16*)alloc((size_t)S * E * 2);
    __hip_bfloat16* kvb   = (__hip_bfloat16*)alloc((size_t)S * 128 * 2);
    __hip_bfloat16* vtb   = (__hip_bfloat16*)alloc((size_t)HD * S * 2);
    __hip_bfloat16* attnb = (__hip_bfloat16*)alloc((size_t)S * E * 2);
    float* bkv = (float*)alloc(512);
    unsigned long long* mbits = (unsigned long long*)alloc((size_t)S * (S / 64) * 8);

    cast_f32_bf16_kernel<<<dim3((S * E / 4 + 255) / 256), dim3(256), 0, stream>>>(x, xb, S * E);
    transpose_cast_kernel<float><<<dim3(E / 32, E / 32), dim3(256), 0, stream>>>(Wq, E, wqT, E, E, E);
    transpose_cast_kernel<float><<<dim3(E / 32, HD / 32), dim3(256), 0, stream>>>(Wk, HD, wkvT, E, E, HD);
    transpose_cast_kernel<float><<<dim3(E / 32, HD / 32), dim3(256), 0, stream>>>(Wv, HD, wkvT + (size_t)HD * E, E, E, HD);
    transpose_cast_kernel<float><<<dim3(E / 32, E / 32), dim3(256), 0, stream>>>(Wo, E, woT, E, E, E);
    concat_bias_kernel<<<dim3(1), dim3(128), 0, stream>>>(bk, bv, bkv);
    maskbits_kernel<<<dim3(1024), dim3(256), 0, stream>>>(mask, mbits, S * (S / 64));

    // q = (x @ Wq + bq) * (1/8 * log2e)  -> bf16 [S][1024]  (log2-domain logits)
    gemm_bt_kernel<__hip_bfloat16><<<dim3((S / 128) * (E / 128)), dim3(256), 0, stream>>>(
        xb, wqT, bq, qb, S, E, E, 0.125f * LOG2E);
    // kv = x @ [Wk|Wv] + [bk|bv]       -> bf16 [S][128]
    gemm_bt_kernel<__hip_bfloat16><<<dim3(S / 128), dim3(256), 0, stream>>>(
        xb, wkvT, bkv, kvb, S, 128, E, 1.0f);
    // v^T [64][S]
    transpose_cast_kernel<__hip_bfloat16><<<dim3(S / 32, HD / 32), dim3(256), 0, stream>>>(
        kvb + HD, 128, vtb, S, S, HD);
    // attention (merged-head MQA, swapped-QK^T flash, gload_lds staging)
    mqa3_kernel<<<dim3(S / 32, NH / 4), dim3(256), 0, stream>>>(qb, kvb, vtb, mbits, attnb, S);
    // out = attn @ Wo + bo  (fp32)
    gemm_bt_kernel<float><<<dim3((S / 128) * (E / 128)), dim3(256), 0, stream>>>(
        attnb, woT, bo, out, S, E, E, 1.0f);
}